// Round 3
// baseline (307.894 us; speedup 1.0000x reference)
//
#include <hip/hip_runtime.h>

// EdgeVar R11: R8's loop body + full residency + dynamic wave-level work
// stealing to kill the static straggler tail.
// Post-mortems R2-R10 established:
//   - The wall is L2 random-request rate: 2E = 25.6M lane-gathers ~= 122us
//     pure-gather floor (R7). Request-count bound: record size doesn't matter.
//   - MLP matters: <8 outstanding gathers/thread starves the pipe (R9: +15us).
//   - Residency matters: 5000 waves vs 8192 cost +13us (R10) -- per-wave
//     iteration latency is queueing-dominated (~20us), needs 8 waves/SIMD.
//   - LDS hist atomics + boundary search ride ~free on the LDS pipe (R5).
//   - Separate passes (R7: +30us) and bucket-sorting (R3/R6: +100us) lose.
// R11: 1024 blocks (exactly 4/CU -> full 32 waves/CU) with MLP=8 body.
// Waves grab 64-group chunks (= one iteration) from 8 per-XCD-ish atomic
// counters (blockIdx&7), each owning a contiguous 1/8 of groups. Next-chunk
// atomic issues before processing current -> latency hidden under gathers.
// 6250 grabs/counter over ~125us = 50/us/counter: negligible contention.

typedef int iv4 __attribute__((ext_vector_type(4)));
typedef unsigned int u32;

#define GBINS 1024
#define NCTR  8
#define CTRSTRIDE 16   // u32s; 64B apart to keep counters on separate lines
#define CHUNK 64       // groups per wave grab = 64 lanes x 1 group (4 edges)

__device__ __forceinline__ int find_graph(int v, const int* __restrict__ ss, float scale) {
    int g = (int)((float)v * scale);       // ~floor(v*G/N); off by a few
    g = min(g, GBINS - 1);
    while (v < ss[g]) --g;                 // ss[0]=0 guards bottom
    while (v >= ss[g + 1]) ++g;            // ss[GBINS]=N guards top
    return g;
}

// startg[1025] from sorted batch_ids; also zeros gsum/gcnt/ctr (replaces memset).
__global__ void prep(const int* __restrict__ batch, int* __restrict__ startg,
                     float* __restrict__ gsum, u32* __restrict__ gcnt,
                     u32* __restrict__ ctr, int N) {
    const int i = blockIdx.x * blockDim.x + threadIdx.x;
    if (i < GBINS) { gsum[i] = 0.f; gcnt[i] = 0u; }
    if (i < NCTR * CTRSTRIDE) ctr[i] = 0u;
    if (i >= N) return;
    const int b = batch[i];
    if (i == 0) { for (int g = 0; g <= b; ++g) startg[g] = 0; }
    else { const int a = batch[i - 1]; for (int g = a + 1; g <= b; ++g) startg[g] = i; }
    if (i == N - 1) { for (int g = b + 1; g <= GBINS; ++g) startg[g] = N; }
}

__global__ __launch_bounds__(512)
void fused_kernel(const int* __restrict__ src, const int* __restrict__ dst,
                  const float2* __restrict__ pos, const int* __restrict__ startg,
                  float* __restrict__ gsum, u32* __restrict__ gcnt,
                  u32* __restrict__ ctr, int E, float scale) {
    __shared__ int ss[GBINS + 1];
    __shared__ float hs[GBINS];
    __shared__ u32 hc[GBINS];
    const int tid = threadIdx.x;
    for (int i = tid; i < GBINS + 1; i += 512) ss[i] = startg[i];
    for (int i = tid; i < GBINS; i += 512) { hs[i] = 0.f; hc[i] = 0u; }
    __syncthreads();

    const int ngroups = E >> 2;            // 4 edges/thread/iter, MLP=8 gathers
    const iv4* __restrict__ s4 = (const iv4*)src;
    const iv4* __restrict__ d4 = (const iv4*)dst;

    // work-stealing range for this block's counter
    const int c   = blockIdx.x & (NCTR - 1);
    const int per = (ngroups + NCTR - 1) / NCTR;
    const int lo  = c * per;
    const int rn  = min(per, ngroups - lo);      // groups in this range
    const int lane = tid & 63;
    u32* __restrict__ myctr = &ctr[c * CTRSTRIDE];

    int cur = 0;
    if (lane == 0) cur = (int)atomicAdd(myctr, (u32)CHUNK);
    cur = __shfl(cur, 0, 64);

    while (cur < rn) {
        int nxt = 0;                              // prefetch next chunk: atomic
        if (lane == 0) nxt = (int)atomicAdd(myctr, (u32)CHUNK);  // latency hides
        const int g_idx = cur + lane;             // under the 8 gathers below
        if (g_idx < rn) {
            const int gi = lo + g_idx;
            const iv4 sv = __builtin_nontemporal_load(&s4[gi]);
            const iv4 dv = __builtin_nontemporal_load(&d4[gi]);
            float2 pa[4], pb[4];
            #pragma unroll
            for (int k = 0; k < 4; ++k) { pa[k] = pos[sv[k]]; pb[k] = pos[dv[k]]; }
            #pragma unroll
            for (int k = 0; k < 4; ++k) {
                const float dx = pb[k].x - pa[k].x;
                const float dy = pb[k].y - pa[k].y;
                const float t  = sqrtf(fmaf(dx, dx, dy * dy)) - 1.f;
                const int g = find_graph(sv[k], ss, scale);
                atomicAdd(&hs[g], t * t);         // LDS pipe: ~free under L2 wall
                atomicAdd(&hc[g], 1u);
            }
        }
        cur = __shfl(nxt, 0, 64);
    }

    // scalar tail for E % 4 (dead at E=12.8M)
    const int gtid = blockIdx.x * 512 + tid, gstride = gridDim.x * 512;
    for (int e = (ngroups << 2) + gtid; e < E; e += gstride) {
        const int s = src[e], d = dst[e];
        const float2 a = pos[s], b = pos[d];
        const float dx = b.x - a.x, dy = b.y - a.y;
        const float t  = sqrtf(fmaf(dx, dx, dy * dy)) - 1.f;
        const int g = find_graph(s, ss, scale);
        atomicAdd(&hs[g], t * t);
        atomicAdd(&hc[g], 1u);
    }

    __syncthreads();
    // striped flush: rotate bin order per block to spread same-address bursts
    for (int j = tid; j < GBINS; j += 512) {
        const int g = (j + (blockIdx.x << 3)) & (GBINS - 1);
        const u32 cc = hc[g];
        if (cc) { atomicAdd(&gcnt[g], cc); atomicAdd(&gsum[g], hs[g]); }
    }
}

__global__ void finalize_kernel(const float* __restrict__ gsum,
                                const u32* __restrict__ gcnt,
                                float* __restrict__ out,
                                const int* __restrict__ nG_ptr) {
    const int G = *nG_ptr;
    float v = 0.f;
    for (int g = threadIdx.x; g < G; g += blockDim.x)
        v += gsum[g] / fmaxf((float)gcnt[g], 1.f);
    __shared__ float w[16];
    for (int off = 32; off; off >>= 1) v += __shfl_down(v, off, 64);
    if ((threadIdx.x & 63) == 0) w[threadIdx.x >> 6] = v;
    __syncthreads();
    if (threadIdx.x == 0) {
        float s = 0.f;
        const int nw = (blockDim.x + 63) >> 6;
        for (int i = 0; i < nw; ++i) s += w[i];
        out[0] = s / (float)G;             // direct store: no d_out memset needed
    }
}

extern "C" void kernel_launch(void* const* d_in, const int* in_sizes, int n_in,
                              void* d_out, int out_size, void* d_ws, size_t ws_size,
                              hipStream_t stream) {
    const float2* pos   = (const float2*)d_in[0];
    const int*    ei    = (const int*)d_in[1];
    const int*    batch = (const int*)d_in[2];
    const int*    nG    = (const int*)d_in[3];

    const int N = in_sizes[0] / 2;
    const int E = in_sizes[1] / 2;
    const int* src = ei;
    const int* dst = ei + E;

    // ws: [gsum 4K][gcnt 4K][startg 1025 ints][pad][ctr 8x64B @12800]
    float* gsum   = (float*)d_ws;
    u32*   gcnt   = (u32*)((char*)d_ws + 4096);
    int*   startg = (int*)((char*)d_ws + 8192);
    u32*   ctr    = (u32*)((char*)d_ws + 12800);

    const float scale = (float)GBINS / (float)N;
    prep<<<(N + 255) / 256, 256, 0, stream>>>(batch, startg, gsum, gcnt, ctr, N);
    // 1024 blocks = exactly 4/CU -> full 32 waves/CU residency (R10 lesson).
    fused_kernel<<<1024, 512, 0, stream>>>(src, dst, pos, startg, gsum, gcnt, ctr, E, scale);
    finalize_kernel<<<1, 1024, 0, stream>>>(gsum, gcnt, (float*)d_out, nG);
}